// Round 1
// baseline (389.817 us; speedup 1.0000x reference)
//
#include <hip/hip_runtime.h>

typedef unsigned short u16;
typedef unsigned int   u32;
typedef __attribute__((ext_vector_type(8))) short short8;
typedef __attribute__((ext_vector_type(4))) float f32x4;
typedef __attribute__((ext_vector_type(2))) float f32x2;

constexpr int BSH = 9;               // bucket = dst >> 9  (512 dsts/bucket)
constexpr int BSZ = 1 << BSH;

__device__ inline float bf2f(u32 bits16) {
    union { u32 u; float f; } c; c.u = bits16 << 16; return c.f;
}
// round-half-up bf16 (cheap: add + shift); |err| <= 0.5 ulp like RNE
__device__ inline u16 f2bf(float f) {
    union { float f; u32 u; } c; c.f = f;
    return (u16)((c.u + 0x8000u) >> 16);
}
// unpack bf16-pair word into float2 (lo, hi)
__device__ inline f32x2 up2(u32 h) {
    union { u32 u[2]; f32x2 f; } c;
    c.u[0] = h << 16;
    c.u[1] = h & 0xffff0000u;
    return c.f;
}
__device__ inline int ld_edge(const void* eb, int f64, size_t idx) {
    return f64 ? (int)((const long long*)eb)[idx] : ((const int*)eb)[idx];
}

// ---------------- dtype detect + bucket cursor init ----------------
__global__ void detect_kernel(const u32* xw, const int* ebuf_int, int* flags,
                              int* bucket_rsv, int nb, int CAP) {
    __shared__ int cnt;
    if (threadIdx.x == 0) cnt = 0;
    __syncthreads();
    u32 w = xw[threadIdx.x];
    int e = (int)((w >> 7) & 0xffu);
    if (e >= 110 && e <= 145) atomicAdd(&cnt, 1);
    int ev = ebuf_int[2 * threadIdx.x + 1];
    unsigned long long any = __ballot(ev != 0);
    if ((int)threadIdx.x < nb) bucket_rsv[threadIdx.x] = threadIdx.x * CAP;
    __syncthreads();
    if (threadIdx.x == 0) {
        flags[0] = (cnt < 192) ? 1 : 0;
        flags[1] = 0;
        flags[2] = (any == 0ULL) ? 1 : 0;
    }
}

// ---------------- bias convert to fp32 ----------------
__global__ void bconv_kernel(const void* b1, const void* b2, const int* flags,
                             float* b1f, float* b2f, int HID, int CLS) {
    int i = blockIdx.x * 256 + threadIdx.x;
    int f = flags[0];
    if (i < HID) b1f[i] = f ? ((const float*)b1)[i] : bf2f(((const u16*)b1)[i]);
    if (i < CLS) b2f[i] = f ? ((const float*)b2)[i] : bf2f(((const u16*)b2)[i]);
}

// ---- passA: single pass, scatter (src,dst) pairs into fixed-cap dst-buckets ----
__global__ __launch_bounds__(256)
void passA_kernel(const void* eb, const int* flags, int* bucket_rsv,
                  int2* bpair, int E, int nb, int CAP) {
    __shared__ int hist[256];
    __shared__ int rbase[256];
    hist[threadIdx.x] = 0;
    __syncthreads();
    int f64 = flags[2];
    int base = blockIdx.x * 8192;
    #pragma unroll
    for (int k = 0; k < 32; ++k) {
        int e = base + k * 256 + threadIdx.x;
        if (e < E) {
            int d = ld_edge(eb, f64, (size_t)E + e);
            atomicAdd(&hist[d >> BSH], 1);
        }
    }
    __syncthreads();
    {
        int b = threadIdx.x;
        int c = (b < nb) ? hist[b] : 0;
        rbase[b] = c ? atomicAdd(&bucket_rsv[b], c) : 0;
        hist[b] = 0;
    }
    __syncthreads();
    #pragma unroll
    for (int k = 0; k < 32; ++k) {
        int e = base + k * 256 + threadIdx.x;
        if (e < E) {
            int d = ld_edge(eb, f64, (size_t)E + e);
            int s = ld_edge(eb, f64, (size_t)e);
            int bb = d >> BSH;
            int r = atomicAdd(&hist[bb], 1);
            int pos = rbase[bb] + r;
            if (pos < (bb + 1) * CAP)          // overflow guard (never for random)
                bpair[pos] = make_int2(s, d);
        }
    }
}

// ---- fillscan: bucket fills -> exclusive scan -> bucket_base; row_start[N]=E ----
__global__ void fillscan_kernel(const int* bucket_rsv, int* bucket_base,
                                int* row_start, int nb, int E, int N, int CAP) {
    __shared__ int wsum[4];
    int t = threadIdx.x, lane = t & 63, wv = t >> 6;
    int v = (t < nb) ? (bucket_rsv[t] - t * CAP) : 0;
    int inc = v;
    #pragma unroll
    for (int d = 1; d < 64; d <<= 1) {
        int tmp = __shfl_up(inc, d, 64);
        if (lane >= d) inc += tmp;
    }
    if (lane == 63) wsum[wv] = inc;
    __syncthreads();
    int off = 0;
    #pragma unroll
    for (int w = 0; w < 4; ++w) if (w < wv) off += wsum[w];
    int excl = off + inc - v;
    if (t <= nb) bucket_base[t] = (t == nb) ? E : excl;
    if (t == 0) row_start[N] = E;
}

// ---- bucketF: per-bucket degree count + local scan -> dinv,row_start,csr ----
__global__ __launch_bounds__(256)
void bucketF_kernel(const int2* __restrict__ bpair, const int* __restrict__ bucket_rsv,
                    const int* __restrict__ bucket_base, float* __restrict__ dinv,
                    int* __restrict__ row_start, int* __restrict__ csr, int N, int CAP) {
    __shared__ int lcnt[BSZ];
    __shared__ int lrow[BSZ];
    __shared__ int wsum[4];
    int b = blockIdx.x, d0 = b << BSH;
    int t = threadIdx.x, lane = t & 63, wv = t >> 6;
    lcnt[2 * t] = 0; lcnt[2 * t + 1] = 0;
    __syncthreads();
    int e0 = b * CAP;
    int e1 = bucket_rsv[b];
    for (int e = e0 + t; e < e1; e += 256)
        atomicAdd(&lcnt[bpair[e].y - d0], 1);
    __syncthreads();
    int c0 = lcnt[2 * t], c1 = lcnt[2 * t + 1];
    int p = c0 + c1;
    int inc = p;
    #pragma unroll
    for (int d = 1; d < 64; d <<= 1) {
        int tmp = __shfl_up(inc, d, 64);
        if (lane >= d) inc += tmp;
    }
    if (lane == 63) wsum[wv] = inc;
    __syncthreads();
    int off = 0;
    #pragma unroll
    for (int w = 0; w < 4; ++w) if (w < wv) off += wsum[w];
    int ex0 = off + inc - p;                 // exclusive prefix for element 2t
    int bb = bucket_base[b];
    lrow[2 * t] = ex0;
    lrow[2 * t + 1] = ex0 + c0;
    int da = d0 + 2 * t, db = d0 + 2 * t + 1;
    if (da < N) { row_start[da] = bb + ex0;      dinv[da] = c0 ? rsqrtf((float)c0) : 0.f; }
    if (db < N) { row_start[db] = bb + ex0 + c0; dinv[db] = c1 ? rsqrtf((float)c1) : 0.f; }
    lcnt[2 * t] = 0; lcnt[2 * t + 1] = 0;    // reuse as cursor
    __syncthreads();
    for (int e = e0 + t; e < e1; e += 256) {
        int2 pr = bpair[e];
        int li = pr.y - d0;
        int r = atomicAdd(&lcnt[li], 1);
        csr[bb + lrow[li] + r] = pr.x;
    }
}

// ------- weight prepack, nt-major: ((nt*KT+kk)*64+lane)*8+j  -------
template<int NT, int KT, int NCOLS>
__global__ void prepack_kernel(const void* W, const int* flags, u16* pack) {
    int p = blockIdx.x * 256 + threadIdx.x;
    constexpr int TOT = NT * KT * 64 * 8;
    if (p >= TOT) return;
    int j = p & 7, lane = (p >> 3) & 63, fk = p >> 9;
    int kk = fk % KT, nt = fk / KT;
    int n = nt * 16 + (lane & 15);
    int k = kk * 32 + (lane >> 4) * 8 + j;
    u16 v = flags[0] ? f2bf(((const float*)W)[k * NCOLS + n])
                     : ((const u16*)W)[k * NCOLS + n];
    pack[p] = v;
}

// ---- gemm1: barrier-free direct-load, N-split; fp32 path is 2-deep
//      software-pipelined (raw loads for kk+1 in flight during kk's MFMA).
//      G=4/NT=2 shrinks acc to 32 AGPRs so the pipeline regs fit. ----
template<int NT, int NTF, int KT, int G>
__global__ __launch_bounds__(256)
void gemm1_kernel(const void* __restrict__ A, const int* __restrict__ ff,
                  const u16* __restrict__ Bpack, const float* __restrict__ dinv,
                  u16* __restrict__ C, int M) {
    constexpr int K = KT * 32;
    constexpr int Ncols = NTF * 16;
    constexpr int NSPLIT = NTF / NT;
    __shared__ short8 lds[NT * KT * 64];
    const int bh = blockIdx.x % NSPLIT;
    const int bm = blockIdx.x / NSPLIT;
    for (int i = threadIdx.x; i < NT * KT * 64; i += 256) {
        int lane_ = i & 63;
        int kk = (i >> 6) % KT;
        int nt = (i >> 6) / KT;
        lds[i] = ((const short8*)Bpack)[(((bh * NT + nt) * KT) + kk) * 64 + lane_];
    }
    bool fA = (*ff != 0);
    int wave = threadIdx.x >> 6, lane = threadIdx.x & 63;
    int m0 = (bm * 4 + wave) * (16 * G);
    int q = lane >> 4, l16 = lane & 15;
    int rowc[G];
    #pragma unroll
    for (int g = 0; g < G; ++g) {
        int r = m0 + g * 16 + l16;
        rowc[g] = (r < M) ? r : (M - 1);
    }
    f32x4 acc[G][NT];
    #pragma unroll
    for (int g = 0; g < G; ++g)
        #pragma unroll
        for (int nt = 0; nt < NT; ++nt) acc[g][nt] = (f32x4){0.f, 0.f, 0.f, 0.f};

    if (fA) {
        const float* Ap[G];
        #pragma unroll
        for (int g = 0; g < G; ++g)
            Ap[g] = (const float*)A + (size_t)rowc[g] * K + q * 8;
        // prologue: issue kk=0 loads before the barrier so they overlap it
        f32x4 raw[2][G][2];
        #pragma unroll
        for (int g = 0; g < G; ++g) {
            raw[0][g][0] = ((const f32x4*)Ap[g])[0];
            raw[0][g][1] = ((const f32x4*)Ap[g])[1];
        }
        __syncthreads();
        if (m0 >= M) return;
        #pragma unroll
        for (int kk = 0; kk < KT; ++kk) {
            const int cur = kk & 1, nxt = cur ^ 1;   // compile-time after unroll
            if (kk + 1 < KT) {
                #pragma unroll
                for (int g = 0; g < G; ++g) {
                    const float* p = Ap[g] + (kk + 1) * 32;
                    raw[nxt][g][0] = ((const f32x4*)p)[0];
                    raw[nxt][g][1] = ((const f32x4*)p)[1];
                }
            }
            short8 a[G];
            #pragma unroll
            for (int g = 0; g < G; ++g) {
                f32x4 v0 = raw[cur][g][0];
                f32x4 v1 = raw[cur][g][1];
                union { short8 s; u16 u[8]; } pa;
                pa.u[0] = f2bf(v0[0]); pa.u[1] = f2bf(v0[1]);
                pa.u[2] = f2bf(v0[2]); pa.u[3] = f2bf(v0[3]);
                pa.u[4] = f2bf(v1[0]); pa.u[5] = f2bf(v1[1]);
                pa.u[6] = f2bf(v1[2]); pa.u[7] = f2bf(v1[3]);
                a[g] = pa.s;
            }
            #pragma unroll
            for (int nt = 0; nt < NT; ++nt) {
                short8 b = lds[(nt * KT + kk) * 64 + lane];
                #pragma unroll
                for (int g = 0; g < G; ++g)
                    acc[g][nt] = __builtin_amdgcn_mfma_f32_16x16x32_bf16(a[g], b, acc[g][nt], 0, 0, 0);
            }
        }
    } else {
        __syncthreads();
        if (m0 >= M) return;
        #pragma unroll
        for (int kk = 0; kk < KT; ++kk) {
            short8 a[G];
            #pragma unroll
            for (int g = 0; g < G; ++g)
                a[g] = ((const short8*)((const u16*)A + (size_t)rowc[g] * K))[kk * 4 + q];
            #pragma unroll
            for (int nt = 0; nt < NT; ++nt) {
                short8 b = lds[(nt * KT + kk) * 64 + lane];
                #pragma unroll
                for (int g = 0; g < G; ++g)
                    acc[g][nt] = __builtin_amdgcn_mfma_f32_16x16x32_bf16(a[g], b, acc[g][nt], 0, 0, 0);
            }
        }
    }

    #pragma unroll
    for (int g = 0; g < G; ++g) {
        float sc[4];
        #pragma unroll
        for (int r = 0; r < 4; ++r) {
            int rr = m0 + g * 16 + q * 4 + r;
            sc[r] = dinv[(rr < M) ? rr : (M - 1)];
        }
        #pragma unroll
        for (int nt = 0; nt < NT; ++nt) {
            int col = bh * (NT * 16) + nt * 16 + l16;
            #pragma unroll
            for (int r = 0; r < 4; ++r) {
                int rrow = m0 + g * 16 + q * 4 + r;
                if (rrow < M)
                    C[(size_t)rrow * Ncols + col] = f2bf(acc[g][nt][r] * sc[r]);
            }
        }
    }
}

// ---- gemm2 (unchanged): A bf16 direct, B (nt-major) in LDS ----
template<int NT, int KT, int G>
__global__ __launch_bounds__(256)
void gemm_kernel(const void* __restrict__ A, const int* __restrict__ ff,
                 const u16* __restrict__ Bpack, const float* __restrict__ dinv,
                 u16* __restrict__ C, int M) {
    constexpr int K = KT * 32;
    constexpr int Ncols = NT * 16;
    __shared__ short8 lds[NT * KT * 64];
    for (int i = threadIdx.x; i < NT * KT * 64; i += 256)
        lds[i] = ((const short8*)Bpack)[i];
    bool fA = (*ff != 0);
    __syncthreads();
    int wave = threadIdx.x >> 6, lane = threadIdx.x & 63;
    int m0 = (blockIdx.x * 4 + wave) * (16 * G);
    if (m0 >= M) return;
    int q = lane >> 4;
    int rowc[G];
    #pragma unroll
    for (int g = 0; g < G; ++g) {
        int r = m0 + g * 16 + (lane & 15);
        rowc[g] = (r < M) ? r : (M - 1);
    }
    f32x4 acc[G][NT];
    #pragma unroll
    for (int g = 0; g < G; ++g)
        #pragma unroll
        for (int nt = 0; nt < NT; ++nt) acc[g][nt] = (f32x4){0.f, 0.f, 0.f, 0.f};
    #pragma unroll
    for (int kk = 0; kk < KT; ++kk) {
        short8 a[G];
        #pragma unroll
        for (int g = 0; g < G; ++g) {
            if (fA) {
                const float* Af = (const float*)A + (size_t)rowc[g] * K + kk * 32 + q * 8;
                f32x4 v0 = ((const f32x4*)Af)[0];
                f32x4 v1 = ((const f32x4*)Af)[1];
                union { short8 s; u16 u[8]; } pa;
                pa.u[0] = f2bf(v0[0]); pa.u[1] = f2bf(v0[1]);
                pa.u[2] = f2bf(v0[2]); pa.u[3] = f2bf(v0[3]);
                pa.u[4] = f2bf(v1[0]); pa.u[5] = f2bf(v1[1]);
                pa.u[6] = f2bf(v1[2]); pa.u[7] = f2bf(v1[3]);
                a[g] = pa.s;
            } else {
                a[g] = ((const short8*)((const u16*)A + (size_t)rowc[g] * K))[kk * 4 + q];
            }
        }
        #pragma unroll
        for (int nt = 0; nt < NT; ++nt) {
            short8 b = lds[(nt * KT + kk) * 64 + lane];
            #pragma unroll
            for (int g = 0; g < G; ++g)
                acc[g][nt] = __builtin_amdgcn_mfma_f32_16x16x32_bf16(a[g], b, acc[g][nt], 0, 0, 0);
        }
    }
    #pragma unroll
    for (int g = 0; g < G; ++g) {
        float sc[4];
        #pragma unroll
        for (int r = 0; r < 4; ++r) {
            int rr = m0 + g * 16 + q * 4 + r;
            sc[r] = dinv[(rr < M) ? rr : (M - 1)];
        }
        #pragma unroll
        for (int nt = 0; nt < NT; ++nt) {
            int col = nt * 16 + (lane & 15);
            #pragma unroll
            for (int r = 0; r < 4; ++r) {
                int rrow = m0 + g * 16 + q * 4 + r;
                if (rrow < M)
                    C[(size_t)rrow * Ncols + col] = f2bf(acc[g][nt][r] * sc[r]);
            }
        }
    }
}

// ---- layer-1 aggregation (unchanged): 8 gathers in flight, packed f32x2 ----
__global__ __launch_bounds__(256)
void agg1_kernel(const u32* __restrict__ H32, const int* __restrict__ csr,
                 const int* __restrict__ row_start, const float* __restrict__ dinv,
                 const float* __restrict__ b1f, u32* __restrict__ H1, int N) {
    int wave = threadIdx.x >> 6, lane = threadIdx.x & 63;
    int n = blockIdx.x * 4 + wave;
    if (n >= N) return;
    int s0 = row_start[n], s1 = row_start[n + 1];
    f32x2 acc = {0.f, 0.f};
    for (int base = s0; base < s1; base += 64) {
        int m = s1 - base; if (m > 64) m = 64;
        int myidx = (lane < m) ? csr[base + lane] : 0;
        int j = 0;
        for (; j + 8 <= m; j += 8) {
            int i0 = __shfl(myidx, j);
            int i1 = __shfl(myidx, j + 1);
            int i2 = __shfl(myidx, j + 2);
            int i3 = __shfl(myidx, j + 3);
            int i4 = __shfl(myidx, j + 4);
            int i5 = __shfl(myidx, j + 5);
            int i6 = __shfl(myidx, j + 6);
            int i7 = __shfl(myidx, j + 7);
            u32 h0 = H32[(size_t)i0 * 64 + lane];
            u32 h1 = H32[(size_t)i1 * 64 + lane];
            u32 h2 = H32[(size_t)i2 * 64 + lane];
            u32 h3 = H32[(size_t)i3 * 64 + lane];
            u32 h4 = H32[(size_t)i4 * 64 + lane];
            u32 h5 = H32[(size_t)i5 * 64 + lane];
            u32 h6 = H32[(size_t)i6 * 64 + lane];
            u32 h7 = H32[(size_t)i7 * 64 + lane];
            f32x2 t0 = up2(h0) + up2(h1);
            f32x2 t1 = up2(h2) + up2(h3);
            f32x2 t2 = up2(h4) + up2(h5);
            f32x2 t3 = up2(h6) + up2(h7);
            acc += (t0 + t1) + (t2 + t3);
        }
        for (; j + 4 <= m; j += 4) {
            int i0 = __shfl(myidx, j);
            int i1 = __shfl(myidx, j + 1);
            int i2 = __shfl(myidx, j + 2);
            int i3 = __shfl(myidx, j + 3);
            u32 h0 = H32[(size_t)i0 * 64 + lane];
            u32 h1 = H32[(size_t)i1 * 64 + lane];
            u32 h2 = H32[(size_t)i2 * 64 + lane];
            u32 h3 = H32[(size_t)i3 * 64 + lane];
            acc += (up2(h0) + up2(h1)) + (up2(h2) + up2(h3));
        }
        for (; j < m; ++j) {
            int s = __shfl(myidx, j);
            acc += up2(H32[(size_t)s * 64 + lane]);
        }
    }
    float wn = dinv[n];
    float v0 = fmaxf(wn * acc.x + b1f[2 * lane], 0.f);
    float v1 = fmaxf(wn * acc.y + b1f[2 * lane + 1], 0.f);
    H1[(size_t)n * 64 + lane] = (u32)f2bf(v0) | ((u32)f2bf(v1) << 16);
}

// ---- layer-2 aggregation + log_softmax: wave/node, 16 lanes/edge, u32 loads ----
// lane = (grp 0..3, l16 0..15); lane handles classes 2*l16, 2*l16+1 of edge grp
__global__ __launch_bounds__(256)
void agg2_kernel(const u32* __restrict__ H2, const int* __restrict__ csr,
                 const int* __restrict__ row_start, const float* __restrict__ dinv,
                 const float* __restrict__ b2f, const int* __restrict__ ff,
                 void* __restrict__ out, int N) {
    int wave = threadIdx.x >> 6, lane = threadIdx.x & 63;
    int n = blockIdx.x * 4 + wave;
    if (n >= N) return;
    int l16 = lane & 15, grp = lane >> 4;
    int s0 = row_start[n], s1 = row_start[n + 1];
    f32x2 acc = {0.f, 0.f};
    for (int base = s0; base < s1; base += 64) {
        int m = s1 - base; if (m > 64) m = 64;
        int myidx = (lane < m) ? csr[base + lane] : 0;
        int j = 0;
        for (; j + 8 <= m; j += 8) {
            int ia = __shfl(myidx, j + grp);
            int ib = __shfl(myidx, j + 4 + grp);
            u32 ha = H2[(size_t)ia * 16 + l16];
            u32 hb = H2[(size_t)ib * 16 + l16];
            acc += up2(ha) + up2(hb);
        }
        for (; j < m; j += 4) {
            int jj = j + grp;
            int iv = __shfl(myidx, (jj < m) ? jj : 0);
            if (jj < m) acc += up2(H2[(size_t)iv * 16 + l16]);
        }
    }
    // reduce across the 4 edge-groups (lanes l16, l16+16, l16+32, l16+48)
    acc.x += __shfl_xor(acc.x, 16); acc.y += __shfl_xor(acc.y, 16);
    acc.x += __shfl_xor(acc.x, 32); acc.y += __shfl_xor(acc.y, 32);
    float wn = dinv[n];
    f32x2 tot;
    tot.x = wn * acc.x + b2f[2 * l16];
    tot.y = wn * acc.y + b2f[2 * l16 + 1];
    float mx = fmaxf(tot.x, tot.y);
    #pragma unroll
    for (int msk = 8; msk; msk >>= 1) mx = fmaxf(mx, __shfl_xor(mx, msk));
    float ex = expf(tot.x - mx) + expf(tot.y - mx);
    #pragma unroll
    for (int msk = 8; msk; msk >>= 1) ex += __shfl_xor(ex, msk);
    float ls = mx + logf(ex);
    if (grp == 0) {
        if (*ff) {
            f32x2 r; r.x = tot.x - ls; r.y = tot.y - ls;
            ((f32x2*)out)[(size_t)n * 16 + l16] = r;
        } else {
            ((u32*)out)[(size_t)n * 16 + l16] =
                (u32)f2bf(tot.x - ls) | ((u32)f2bf(tot.y - ls) << 16);
        }
    }
}

extern "C" void kernel_launch(void* const* d_in, const int* in_sizes, int n_in,
                              void* d_out, int out_size, void* d_ws, size_t ws_size,
                              hipStream_t stream) {
    const void* x  = d_in[0];
    const void* W1 = d_in[1];
    const void* b1 = d_in[2];
    const void* W2 = d_in[3];
    const void* b2 = d_in[4];
    const void* eb = d_in[5];

    const int HID  = in_sizes[2];            // 128
    const int CLS  = in_sizes[4];            // 32
    const int FEAT = in_sizes[1] / HID;      // 256
    const int N    = in_sizes[0] / FEAT;     // 100000
    const int E    = in_sizes[5] / 2;        // 1600000
    const int nb   = (N + BSZ - 1) >> BSH;   // 196 (assumes <= 256)
    const int CAP  = (((4 * (E / nb)) >> 10) + 2) << 10;   // ~4x avg fill, 1K-rounded
    (void)n_in; (void)out_size;

    char* w = (char*)d_ws;
    size_t p = 0;
    auto alloc = [&](size_t bytes) {
        size_t o = p; p = (p + bytes + 255) & ~(size_t)255; return o;
    };
    int*   flags      = (int*)  (w + alloc(32));
    int*   row_start  = (int*)  (w + alloc((size_t)(N + 1) * 4));
    int*   bucket_base= (int*)  (w + alloc(257 * 4));
    int*   bucket_rsv = (int*)  (w + alloc(256 * 4));
    int2*  bpair      = (int2*) (w + alloc((size_t)nb * CAP * 8));
    int*   csr        = (int*)  (w + alloc((size_t)E * 4));
    float* dinv       = (float*)(w + alloc((size_t)N * 4));
    float* b1f        = (float*)(w + alloc((size_t)HID * 4));
    float* b2f        = (float*)(w + alloc((size_t)CLS * 4));
    u16*   B1p        = (u16*)  (w + alloc((size_t)FEAT * HID * 2));
    u16*   B2p        = (u16*)  (w + alloc((size_t)HID * CLS * 2));
    u16*   H          = (u16*)  (w + alloc((size_t)N * HID * 2));
    u16*   H1         = (u16*)  (w + alloc((size_t)N * HID * 2));
    u16*   H2         = (u16*)  (w + alloc((size_t)N * CLS * 2));
    if (p > ws_size) return;   // workspace too small: fail visibly

    detect_kernel<<<1, 256, 0, stream>>>((const u32*)x, (const int*)eb, flags,
                                         bucket_rsv, nb, CAP);
    bconv_kernel<<<1, 256, 0, stream>>>(b1, b2, flags, b1f, b2f, HID, CLS);

    passA_kernel<<<(E + 8191) / 8192, 256, 0, stream>>>(eb, flags, bucket_rsv,
                                                        bpair, E, nb, CAP);
    fillscan_kernel<<<1, 256, 0, stream>>>(bucket_rsv, bucket_base, row_start,
                                           nb, E, N, CAP);
    bucketF_kernel<<<nb, 256, 0, stream>>>(bpair, bucket_rsv, bucket_base,
                                           dinv, row_start, csr, N, CAP);

    prepack_kernel<8, 8, 128><<<(8 * 8 * 64 * 8 + 255) / 256, 256, 0, stream>>>(W1, flags, B1p);
    prepack_kernel<2, 4, 32><<<(2 * 4 * 64 * 8 + 255) / 256, 256, 0, stream>>>(W2, flags, B2p);

    // gemm1: N-split in 4 col-quarters (NT=2 of NTF=8), G=4 -> 256-row blocks,
    // 2-deep pipelined fp32 A loads (8 dwordx4 in flight per wave)
    gemm1_kernel<2, 8, 8, 4><<<4 * ((N + 255) / 256), 256, 0, stream>>>(x, flags, B1p, dinv, H, N);
    agg1_kernel<<<(N + 3) / 4, 256, 0, stream>>>((const u32*)H, csr, row_start, dinv, b1f,
                                                 (u32*)H1, N);
    gemm_kernel<2, 4, 2><<<(N + 127) / 128, 256, 0, stream>>>(H1, flags + 1, B2p, dinv, H2, N);
    agg2_kernel<<<(N + 3) / 4, 256, 0, stream>>>((const u32*)H2, csr, row_start, dinv, b2f,
                                                 flags, (void*)d_out, N);
}

// Round 4
// 377.220 us; speedup vs baseline: 1.0334x; 1.0334x over previous
//
#include <hip/hip_runtime.h>

typedef unsigned short u16;
typedef unsigned int   u32;
typedef __attribute__((ext_vector_type(8))) short short8;
typedef __attribute__((ext_vector_type(4))) float f32x4;
typedef __attribute__((ext_vector_type(2))) float f32x2;

constexpr int BSH = 9;               // bucket = dst >> 9  (512 dsts/bucket)
constexpr int BSZ = 1 << BSH;

__device__ inline float bf2f(u32 bits16) {
    union { u32 u; float f; } c; c.u = bits16 << 16; return c.f;
}
// round-half-up bf16 (cheap: add + shift); |err| <= 0.5 ulp like RNE
__device__ inline u16 f2bf(float f) {
    union { float f; u32 u; } c; c.f = f;
    return (u16)((c.u + 0x8000u) >> 16);
}
// unpack bf16-pair word into float2 (lo, hi)
__device__ inline f32x2 up2(u32 h) {
    union { u32 u[2]; f32x2 f; } c;
    c.u[0] = h << 16;
    c.u[1] = h & 0xffff0000u;
    return c.f;
}
__device__ inline int ld_edge(const void* eb, int f64, size_t idx) {
    return f64 ? (int)((const long long*)eb)[idx] : ((const int*)eb)[idx];
}
// async global->LDS, 16B per lane (1 KB per wave-instruction in flight)
__device__ inline void gl16(const void* g, void* l) {
    __builtin_amdgcn_global_load_lds(
        (const __attribute__((address_space(1))) unsigned int*)g,
        (__attribute__((address_space(3))) unsigned int*)l, 16, 0, 0);
}

// ---------------- dtype detect + bucket cursor init ----------------
__global__ void detect_kernel(const u32* xw, const int* ebuf_int, int* flags,
                              int* bucket_rsv, int nb, int CAP) {
    __shared__ int cnt;
    if (threadIdx.x == 0) cnt = 0;
    __syncthreads();
    u32 w = xw[threadIdx.x];
    int e = (int)((w >> 7) & 0xffu);
    if (e >= 110 && e <= 145) atomicAdd(&cnt, 1);
    int ev = ebuf_int[2 * threadIdx.x + 1];
    unsigned long long any = __ballot(ev != 0);
    if ((int)threadIdx.x < nb) bucket_rsv[threadIdx.x] = threadIdx.x * CAP;
    __syncthreads();
    if (threadIdx.x == 0) {
        flags[0] = (cnt < 192) ? 1 : 0;
        flags[1] = 0;
        flags[2] = (any == 0ULL) ? 1 : 0;
    }
}

// ---------------- bias convert to fp32 ----------------
__global__ void bconv_kernel(const void* b1, const void* b2, const int* flags,
                             float* b1f, float* b2f, int HID, int CLS) {
    int i = blockIdx.x * 256 + threadIdx.x;
    int f = flags[0];
    if (i < HID) b1f[i] = f ? ((const float*)b1)[i] : bf2f(((const u16*)b1)[i]);
    if (i < CLS) b2f[i] = f ? ((const float*)b2)[i] : bf2f(((const u16*)b2)[i]);
}

// ---- passA: single pass, scatter (src,dst) pairs into fixed-cap dst-buckets ----
__global__ __launch_bounds__(256)
void passA_kernel(const void* eb, const int* flags, int* bucket_rsv,
                  int2* bpair, int E, int nb, int CAP) {
    __shared__ int hist[256];
    __shared__ int rbase[256];
    hist[threadIdx.x] = 0;
    __syncthreads();
    int f64 = flags[2];
    int base = blockIdx.x * 8192;
    #pragma unroll
    for (int k = 0; k < 32; ++k) {
        int e = base + k * 256 + threadIdx.x;
        if (e < E) {
            int d = ld_edge(eb, f64, (size_t)E + e);
            atomicAdd(&hist[d >> BSH], 1);
        }
    }
    __syncthreads();
    {
        int b = threadIdx.x;
        int c = (b < nb) ? hist[b] : 0;
        rbase[b] = c ? atomicAdd(&bucket_rsv[b], c) : 0;
        hist[b] = 0;
    }
    __syncthreads();
    #pragma unroll
    for (int k = 0; k < 32; ++k) {
        int e = base + k * 256 + threadIdx.x;
        if (e < E) {
            int d = ld_edge(eb, f64, (size_t)E + e);
            int s = ld_edge(eb, f64, (size_t)e);
            int bb = d >> BSH;
            int r = atomicAdd(&hist[bb], 1);
            int pos = rbase[bb] + r;
            if (pos < (bb + 1) * CAP)          // overflow guard (never for random)
                bpair[pos] = make_int2(s, d);
        }
    }
}

// ---- fillscan: bucket fills -> exclusive scan -> bucket_base; row_start[N]=E ----
__global__ void fillscan_kernel(const int* bucket_rsv, int* bucket_base,
                                int* row_start, int nb, int E, int N, int CAP) {
    __shared__ int wsum[4];
    int t = threadIdx.x, lane = t & 63, wv = t >> 6;
    int v = (t < nb) ? (bucket_rsv[t] - t * CAP) : 0;
    int inc = v;
    #pragma unroll
    for (int d = 1; d < 64; d <<= 1) {
        int tmp = __shfl_up(inc, d, 64);
        if (lane >= d) inc += tmp;
    }
    if (lane == 63) wsum[wv] = inc;
    __syncthreads();
    int off = 0;
    #pragma unroll
    for (int w = 0; w < 4; ++w) if (w < wv) off += wsum[w];
    int excl = off + inc - v;
    if (t <= nb) bucket_base[t] = (t == nb) ? E : excl;
    if (t == 0) row_start[N] = E;
}

// ---- bucketF: per-bucket degree count + local scan -> dinv,row_start,csr ----
__global__ __launch_bounds__(256)
void bucketF_kernel(const int2* __restrict__ bpair, const int* __restrict__ bucket_rsv,
                    const int* __restrict__ bucket_base, float* __restrict__ dinv,
                    int* __restrict__ row_start, int* __restrict__ csr, int N, int CAP) {
    __shared__ int lcnt[BSZ];
    __shared__ int lrow[BSZ];
    __shared__ int wsum[4];
    int b = blockIdx.x, d0 = b << BSH;
    int t = threadIdx.x, lane = t & 63, wv = t >> 6;
    lcnt[2 * t] = 0; lcnt[2 * t + 1] = 0;
    __syncthreads();
    int e0 = b * CAP;
    int e1 = bucket_rsv[b];
    for (int e = e0 + t; e < e1; e += 256)
        atomicAdd(&lcnt[bpair[e].y - d0], 1);
    __syncthreads();
    int c0 = lcnt[2 * t], c1 = lcnt[2 * t + 1];
    int p = c0 + c1;
    int inc = p;
    #pragma unroll
    for (int d = 1; d < 64; d <<= 1) {
        int tmp = __shfl_up(inc, d, 64);
        if (lane >= d) inc += tmp;
    }
    if (lane == 63) wsum[wv] = inc;
    __syncthreads();
    int off = 0;
    #pragma unroll
    for (int w = 0; w < 4; ++w) if (w < wv) off += wsum[w];
    int ex0 = off + inc - p;                 // exclusive prefix for element 2t
    int bb = bucket_base[b];
    lrow[2 * t] = ex0;
    lrow[2 * t + 1] = ex0 + c0;
    int da = d0 + 2 * t, db = d0 + 2 * t + 1;
    if (da < N) { row_start[da] = bb + ex0;      dinv[da] = c0 ? rsqrtf((float)c0) : 0.f; }
    if (db < N) { row_start[db] = bb + ex0 + c0; dinv[db] = c1 ? rsqrtf((float)c1) : 0.f; }
    lcnt[2 * t] = 0; lcnt[2 * t + 1] = 0;    // reuse as cursor
    __syncthreads();
    for (int e = e0 + t; e < e1; e += 256) {
        int2 pr = bpair[e];
        int li = pr.y - d0;
        int r = atomicAdd(&lcnt[li], 1);
        csr[bb + lrow[li] + r] = pr.x;
    }
}

// ------- weight prepack, nt-major: ((nt*KT+kk)*64+lane)*8+j  -------
template<int NT, int KT, int NCOLS>
__global__ void prepack_kernel(const void* W, const int* flags, u16* pack) {
    int p = blockIdx.x * 256 + threadIdx.x;
    constexpr int TOT = NT * KT * 64 * 8;
    if (p >= TOT) return;
    int j = p & 7, lane = (p >> 3) & 63, fk = p >> 9;
    int kk = fk % KT, nt = fk / KT;
    int n = nt * 16 + (lane & 15);
    int k = kk * 32 + (lane >> 4) * 8 + j;
    u16 v = flags[0] ? f2bf(((const float*)W)[k * NCOLS + n])
                     : ((const u16*)W)[k * NCOLS + n];
    pack[p] = v;
}

// ---- gemm1: LDS-staged fp32 A via global_load_lds, 3-buffer ring,
//      counted vmcnt (never drained in loop), raw s_barrier (1/step)
//      emitted as asm volatile w/ memory clobber so the compiler cannot
//      move LDS/VMEM ops across it (llvm.amdgcn.s.barrier is NoMem).
//      Source-address XOR-swizzle (16B slot: sl^=row&7) keeps LDS dest
//      linear (gload_lds requirement) while making stride-128B ds_reads
//      conflict-free. NSPLIT=2 pairs adjacent blocks so duplicate A
//      reads are cache-absorbed (proven: FETCH == 1x X). ----
template<int NT, int NTF, int KT, int G>
__global__ __launch_bounds__(256)
void gemm1_kernel(const void* __restrict__ A, const int* __restrict__ ff,
                  const u16* __restrict__ Bpack, const float* __restrict__ dinv,
                  u16* __restrict__ C, int M) {
    constexpr int K = KT * 32;          // 256
    constexpr int Ncols = NTF * 16;     // 128
    constexpr int NSPLIT = NTF / NT;    // 2
    constexpr int BM = 4 * 16 * G;      // 128 rows per block
    constexpr int ABUF = BM * 32 * 4;   // 16 KB per K-step tile
    constexpr int BBYTES = NT * KT * 64 * 16;  // 32 KB
    __shared__ __align__(16) char ldsA[3 * ABUF];
    __shared__ short8 ldsB[NT * KT * 64];

    const int bh = blockIdx.x % NSPLIT;
    const int bm = blockIdx.x / NSPLIT;
    const int t  = threadIdx.x;

    // ---- stage B (32 KB) via global_load_lds, linear ----
    {
        const char* gB = (const char*)Bpack + (size_t)bh * BBYTES;
        char* lB = (char*)ldsB;
        #pragma unroll
        for (int c = 0; c < BBYTES / 4096; ++c)
            gl16(gB + c * 4096 + t * 16, lB + c * 4096 + t * 16);
    }
    const bool fA = (*ff != 0);
    const int wave = t >> 6, lane = t & 63;
    const int m0 = (bm * 4 + wave) * (16 * G);
    const int q = lane >> 4, l16 = lane & 15;

    f32x4 acc[G][NT];
    #pragma unroll
    for (int g = 0; g < G; ++g)
        #pragma unroll
        for (int nt = 0; nt < NT; ++nt) acc[g][nt] = (f32x4){0.f, 0.f, 0.f, 0.f};

    if (fA) {
        // per-thread staging geometry: thread t covers row rb of each 32-row
        // chunk c, 16B slot sl; global slot pre-swizzled so LDS stays linear.
        const int rb = t >> 3;               // 0..31
        const int sl = t & 7;
        const int sg = sl ^ (rb & 7);        // source-side swizzle (16B slots)
        const float* gp[4];
        #pragma unroll
        for (int c = 0; c < 4; ++c) {
            int r = bm * BM + c * 32 + rb;
            if (r > M - 1) r = M - 1;        // tail clamp (reads only)
            gp[c] = (const float*)A + (size_t)r * K + sg * 4;   // 16B slot = 4 floats
        }
        // per-thread read offsets (constant across kk; buffer base varies)
        int off0[G], off1[G];
        #pragma unroll
        for (int g = 0; g < G; ++g) {
            int row_l = wave * (16 * G) + g * 16 + l16;
            int r7 = row_l & 7;
            off0[g] = row_l * 128 + ((2 * q) ^ r7) * 16;
            off1[g] = row_l * 128 + ((2 * q + 1) ^ r7) * 16;
        }
        // prologue: stage kk=0 -> buf0, kk=1 -> buf1 (8 instr/wave in flight)
        #pragma unroll
        for (int pj = 0; pj < 2; ++pj) {
            char* lb = ldsA + pj * ABUF + t * 16;
            #pragma unroll
            for (int c = 0; c < 4; ++c)
                gl16(gp[c] + pj * 32, lb + c * 4096);
        }
        #pragma unroll
        for (int kk = 0; kk < KT; ++kk) {
            // counted wait: leave next tile's 4 loads in flight (never 0
            // until the last step); then sync so ALL waves' parts landed.
            if (kk == KT - 1) asm volatile("s_waitcnt vmcnt(0)" ::: "memory");
            else              asm volatile("s_waitcnt vmcnt(4)" ::: "memory");
            asm volatile("s_barrier" ::: "memory");
            if (kk + 2 < KT) {   // stage kk+2 into ring slot (read kk-1 done)
                char* lb = ldsA + ((kk + 2) % 3) * ABUF + t * 16;
                #pragma unroll
                for (int c = 0; c < 4; ++c)
                    gl16(gp[c] + (kk + 2) * 32, lb + c * 4096);
            }
            const char* ab = ldsA + (kk % 3) * ABUF;
            short8 a[G];
            #pragma unroll
            for (int g = 0; g < G; ++g) {
                f32x4 v0 = *(const f32x4*)(ab + off0[g]);
                f32x4 v1 = *(const f32x4*)(ab + off1[g]);
                union { short8 s; u16 u[8]; } pa;
                pa.u[0] = f2bf(v0[0]); pa.u[1] = f2bf(v0[1]);
                pa.u[2] = f2bf(v0[2]); pa.u[3] = f2bf(v0[3]);
                pa.u[4] = f2bf(v1[0]); pa.u[5] = f2bf(v1[1]);
                pa.u[6] = f2bf(v1[2]); pa.u[7] = f2bf(v1[3]);
                a[g] = pa.s;
            }
            #pragma unroll
            for (int nt = 0; nt < NT; ++nt) {
                short8 b = ldsB[(nt * KT + kk) * 64 + lane];
                #pragma unroll
                for (int g = 0; g < G; ++g)
                    acc[g][nt] = __builtin_amdgcn_mfma_f32_16x16x32_bf16(a[g], b, acc[g][nt], 0, 0, 0);
            }
        }
    } else {
        // bf16 input: direct per-row loads (B staged above; drain + sync)
        asm volatile("s_waitcnt vmcnt(0)" ::: "memory");
        asm volatile("s_barrier" ::: "memory");
        int rowc[G];
        #pragma unroll
        for (int g = 0; g < G; ++g) {
            int r = m0 + g * 16 + l16;
            rowc[g] = (r < M) ? r : (M - 1);
        }
        #pragma unroll
        for (int kk = 0; kk < KT; ++kk) {
            short8 a[G];
            #pragma unroll
            for (int g = 0; g < G; ++g)
                a[g] = ((const short8*)((const u16*)A + (size_t)rowc[g] * K))[kk * 4 + q];
            #pragma unroll
            for (int nt = 0; nt < NT; ++nt) {
                short8 b = ldsB[(nt * KT + kk) * 64 + lane];
                #pragma unroll
                for (int g = 0; g < G; ++g)
                    acc[g][nt] = __builtin_amdgcn_mfma_f32_16x16x32_bf16(a[g], b, acc[g][nt], 0, 0, 0);
            }
        }
    }

    #pragma unroll
    for (int g = 0; g < G; ++g) {
        float sc[4];
        #pragma unroll
        for (int r = 0; r < 4; ++r) {
            int rr = m0 + g * 16 + q * 4 + r;
            sc[r] = dinv[(rr < M) ? rr : (M - 1)];
        }
        #pragma unroll
        for (int nt = 0; nt < NT; ++nt) {
            int col = bh * (NT * 16) + nt * 16 + l16;
            #pragma unroll
            for (int r = 0; r < 4; ++r) {
                int rrow = m0 + g * 16 + q * 4 + r;
                if (rrow < M)
                    C[(size_t)rrow * Ncols + col] = f2bf(acc[g][nt][r] * sc[r]);
            }
        }
    }
}

// ---- gemm2 (unchanged): A bf16 direct, B (nt-major) in LDS ----
template<int NT, int KT, int G>
__global__ __launch_bounds__(256)
void gemm_kernel(const void* __restrict__ A, const int* __restrict__ ff,
                 const u16* __restrict__ Bpack, const float* __restrict__ dinv,
                 u16* __restrict__ C, int M) {
    constexpr int K = KT * 32;
    constexpr int Ncols = NT * 16;
    __shared__ short8 lds[NT * KT * 64];
    for (int i = threadIdx.x; i < NT * KT * 64; i += 256)
        lds[i] = ((const short8*)Bpack)[i];
    bool fA = (*ff != 0);
    __syncthreads();
    int wave = threadIdx.x >> 6, lane = threadIdx.x & 63;
    int m0 = (blockIdx.x * 4 + wave) * (16 * G);
    if (m0 >= M) return;
    int q = lane >> 4;
    int rowc[G];
    #pragma unroll
    for (int g = 0; g < G; ++g) {
        int r = m0 + g * 16 + (lane & 15);
        rowc[g] = (r < M) ? r : (M - 1);
    }
    f32x4 acc[G][NT];
    #pragma unroll
    for (int g = 0; g < G; ++g)
        #pragma unroll
        for (int nt = 0; nt < NT; ++nt) acc[g][nt] = (f32x4){0.f, 0.f, 0.f, 0.f};
    #pragma unroll
    for (int kk = 0; kk < KT; ++kk) {
        short8 a[G];
        #pragma unroll
        for (int g = 0; g < G; ++g) {
            if (fA) {
                const float* Af = (const float*)A + (size_t)rowc[g] * K + kk * 32 + q * 8;
                f32x4 v0 = ((const f32x4*)Af)[0];
                f32x4 v1 = ((const f32x4*)Af)[1];
                union { short8 s; u16 u[8]; } pa;
                pa.u[0] = f2bf(v0[0]); pa.u[1] = f2bf(v0[1]);
                pa.u[2] = f2bf(v0[2]); pa.u[3] = f2bf(v0[3]);
                pa.u[4] = f2bf(v1[0]); pa.u[5] = f2bf(v1[1]);
                pa.u[6] = f2bf(v1[2]); pa.u[7] = f2bf(v1[3]);
                a[g] = pa.s;
            } else {
                a[g] = ((const short8*)((const u16*)A + (size_t)rowc[g] * K))[kk * 4 + q];
            }
        }
        #pragma unroll
        for (int nt = 0; nt < NT; ++nt) {
            short8 b = lds[(nt * KT + kk) * 64 + lane];
            #pragma unroll
            for (int g = 0; g < G; ++g)
                acc[g][nt] = __builtin_amdgcn_mfma_f32_16x16x32_bf16(a[g], b, acc[g][nt], 0, 0, 0);
        }
    }
    #pragma unroll
    for (int g = 0; g < G; ++g) {
        float sc[4];
        #pragma unroll
        for (int r = 0; r < 4; ++r) {
            int rr = m0 + g * 16 + q * 4 + r;
            sc[r] = dinv[(rr < M) ? rr : (M - 1)];
        }
        #pragma unroll
        for (int nt = 0; nt < NT; ++nt) {
            int col = nt * 16 + (lane & 15);
            #pragma unroll
            for (int r = 0; r < 4; ++r) {
                int rrow = m0 + g * 16 + q * 4 + r;
                if (rrow < M)
                    C[(size_t)rrow * Ncols + col] = f2bf(acc[g][nt][r] * sc[r]);
            }
        }
    }
}

// ---- layer-1 aggregation (unchanged): 8 gathers in flight, packed f32x2 ----
__global__ __launch_bounds__(256)
void agg1_kernel(const u32* __restrict__ H32, const int* __restrict__ csr,
                 const int* __restrict__ row_start, const float* __restrict__ dinv,
                 const float* __restrict__ b1f, u32* __restrict__ H1, int N) {
    int wave = threadIdx.x >> 6, lane = threadIdx.x & 63;
    int n = blockIdx.x * 4 + wave;
    if (n >= N) return;
    int s0 = row_start[n], s1 = row_start[n + 1];
    f32x2 acc = {0.f, 0.f};
    for (int base = s0; base < s1; base += 64) {
        int m = s1 - base; if (m > 64) m = 64;
        int myidx = (lane < m) ? csr[base + lane] : 0;
        int j = 0;
        for (; j + 8 <= m; j += 8) {
            int i0 = __shfl(myidx, j);
            int i1 = __shfl(myidx, j + 1);
            int i2 = __shfl(myidx, j + 2);
            int i3 = __shfl(myidx, j + 3);
            int i4 = __shfl(myidx, j + 4);
            int i5 = __shfl(myidx, j + 5);
            int i6 = __shfl(myidx, j + 6);
            int i7 = __shfl(myidx, j + 7);
            u32 h0 = H32[(size_t)i0 * 64 + lane];
            u32 h1 = H32[(size_t)i1 * 64 + lane];
            u32 h2 = H32[(size_t)i2 * 64 + lane];
            u32 h3 = H32[(size_t)i3 * 64 + lane];
            u32 h4 = H32[(size_t)i4 * 64 + lane];
            u32 h5 = H32[(size_t)i5 * 64 + lane];
            u32 h6 = H32[(size_t)i6 * 64 + lane];
            u32 h7 = H32[(size_t)i7 * 64 + lane];
            f32x2 t0 = up2(h0) + up2(h1);
            f32x2 t1 = up2(h2) + up2(h3);
            f32x2 t2 = up2(h4) + up2(h5);
            f32x2 t3 = up2(h6) + up2(h7);
            acc += (t0 + t1) + (t2 + t3);
        }
        for (; j + 4 <= m; j += 4) {
            int i0 = __shfl(myidx, j);
            int i1 = __shfl(myidx, j + 1);
            int i2 = __shfl(myidx, j + 2);
            int i3 = __shfl(myidx, j + 3);
            u32 h0 = H32[(size_t)i0 * 64 + lane];
            u32 h1 = H32[(size_t)i1 * 64 + lane];
            u32 h2 = H32[(size_t)i2 * 64 + lane];
            u32 h3 = H32[(size_t)i3 * 64 + lane];
            acc += (up2(h0) + up2(h1)) + (up2(h2) + up2(h3));
        }
        for (; j < m; ++j) {
            int s = __shfl(myidx, j);
            acc += up2(H32[(size_t)s * 64 + lane]);
        }
    }
    float wn = dinv[n];
    float v0 = fmaxf(wn * acc.x + b1f[2 * lane], 0.f);
    float v1 = fmaxf(wn * acc.y + b1f[2 * lane + 1], 0.f);
    H1[(size_t)n * 64 + lane] = (u32)f2bf(v0) | ((u32)f2bf(v1) << 16);
}

// ---- layer-2 aggregation + log_softmax: wave/node, 16 lanes/edge, u32 loads ----
// lane = (grp 0..3, l16 0..15); lane handles classes 2*l16, 2*l16+1 of edge grp
__global__ __launch_bounds__(256)
void agg2_kernel(const u32* __restrict__ H2, const int* __restrict__ csr,
                 const int* __restrict__ row_start, const float* __restrict__ dinv,
                 const float* __restrict__ b2f, const int* __restrict__ ff,
                 void* __restrict__ out, int N) {
    int wave = threadIdx.x >> 6, lane = threadIdx.x & 63;
    int n = blockIdx.x * 4 + wave;
    if (n >= N) return;
    int l16 = lane & 15, grp = lane >> 4;
    int s0 = row_start[n], s1 = row_start[n + 1];
    f32x2 acc = {0.f, 0.f};
    for (int base = s0; base < s1; base += 64) {
        int m = s1 - base; if (m > 64) m = 64;
        int myidx = (lane < m) ? csr[base + lane] : 0;
        int j = 0;
        for (; j + 8 <= m; j += 8) {
            int ia = __shfl(myidx, j + grp);
            int ib = __shfl(myidx, j + 4 + grp);
            u32 ha = H2[(size_t)ia * 16 + l16];
            u32 hb = H2[(size_t)ib * 16 + l16];
            acc += up2(ha) + up2(hb);
        }
        for (; j < m; j += 4) {
            int jj = j + grp;
            int iv = __shfl(myidx, (jj < m) ? jj : 0);
            if (jj < m) acc += up2(H2[(size_t)iv * 16 + l16]);
        }
    }
    // reduce across the 4 edge-groups (lanes l16, l16+16, l16+32, l16+48)
    acc.x += __shfl_xor(acc.x, 16); acc.y += __shfl_xor(acc.y, 16);
    acc.x += __shfl_xor(acc.x, 32); acc.y += __shfl_xor(acc.y, 32);
    float wn = dinv[n];
    f32x2 tot;
    tot.x = wn * acc.x + b2f[2 * l16];
    tot.y = wn * acc.y + b2f[2 * l16 + 1];
    float mx = fmaxf(tot.x, tot.y);
    #pragma unroll
    for (int msk = 8; msk; msk >>= 1) mx = fmaxf(mx, __shfl_xor(mx, msk));
    float ex = expf(tot.x - mx) + expf(tot.y - mx);
    #pragma unroll
    for (int msk = 8; msk; msk >>= 1) ex += __shfl_xor(ex, msk);
    float ls = mx + logf(ex);
    if (grp == 0) {
        if (*ff) {
            f32x2 r; r.x = tot.x - ls; r.y = tot.y - ls;
            ((f32x2*)out)[(size_t)n * 16 + l16] = r;
        } else {
            ((u32*)out)[(size_t)n * 16 + l16] =
                (u32)f2bf(tot.x - ls) | ((u32)f2bf(tot.y - ls) << 16);
        }
    }
}

extern "C" void kernel_launch(void* const* d_in, const int* in_sizes, int n_in,
                              void* d_out, int out_size, void* d_ws, size_t ws_size,
                              hipStream_t stream) {
    const void* x  = d_in[0];
    const void* W1 = d_in[1];
    const void* b1 = d_in[2];
    const void* W2 = d_in[3];
    const void* b2 = d_in[4];
    const void* eb = d_in[5];

    const int HID  = in_sizes[2];            // 128
    const int CLS  = in_sizes[4];            // 32
    const int FEAT = in_sizes[1] / HID;      // 256
    const int N    = in_sizes[0] / FEAT;     // 100000
    const int E    = in_sizes[5] / 2;        // 1600000
    const int nb   = (N + BSZ - 1) >> BSH;   // 196 (assumes <= 256)
    const int CAP  = (((4 * (E / nb)) >> 10) + 2) << 10;   // ~4x avg fill, 1K-rounded
    (void)n_in; (void)out_size;

    char* w = (char*)d_ws;
    size_t p = 0;
    auto alloc = [&](size_t bytes) {
        size_t o = p; p = (p + bytes + 255) & ~(size_t)255; return o;
    };
    int*   flags      = (int*)  (w + alloc(32));
    int*   row_start  = (int*)  (w + alloc((size_t)(N + 1) * 4));
    int*   bucket_base= (int*)  (w + alloc(257 * 4));
    int*   bucket_rsv = (int*)  (w + alloc(256 * 4));
    int2*  bpair      = (int2*) (w + alloc((size_t)nb * CAP * 8));
    int*   csr        = (int*)  (w + alloc((size_t)E * 4));
    float* dinv       = (float*)(w + alloc((size_t)N * 4));
    float* b1f        = (float*)(w + alloc((size_t)HID * 4));
    float* b2f        = (float*)(w + alloc((size_t)CLS * 4));
    u16*   B1p        = (u16*)  (w + alloc((size_t)FEAT * HID * 2));
    u16*   B2p        = (u16*)  (w + alloc((size_t)HID * CLS * 2));
    u16*   H          = (u16*)  (w + alloc((size_t)N * HID * 2));
    u16*   H1         = (u16*)  (w + alloc((size_t)N * HID * 2));
    u16*   H2         = (u16*)  (w + alloc((size_t)N * CLS * 2));
    if (p > ws_size) return;   // workspace too small: fail visibly

    detect_kernel<<<1, 256, 0, stream>>>((const u32*)x, (const int*)eb, flags,
                                         bucket_rsv, nb, CAP);
    bconv_kernel<<<1, 256, 0, stream>>>(b1, b2, flags, b1f, b2f, HID, CLS);

    passA_kernel<<<(E + 8191) / 8192, 256, 0, stream>>>(eb, flags, bucket_rsv,
                                                        bpair, E, nb, CAP);
    fillscan_kernel<<<1, 256, 0, stream>>>(bucket_rsv, bucket_base, row_start,
                                           nb, E, N, CAP);
    bucketF_kernel<<<nb, 256, 0, stream>>>(bpair, bucket_rsv, bucket_base,
                                           dinv, row_start, csr, N, CAP);

    prepack_kernel<8, 8, 128><<<(8 * 8 * 64 * 8 + 255) / 256, 256, 0, stream>>>(W1, flags, B1p);
    prepack_kernel<2, 4, 32><<<(2 * 4 * 64 * 8 + 255) / 256, 256, 0, stream>>>(W2, flags, B2p);

    // gemm1: LDS-staged (global_load_lds ring), 2-way N-split, 128-row stripes
    gemm1_kernel<4, 8, 8, 2><<<2 * ((N + 127) / 128), 256, 0, stream>>>(x, flags, B1p, dinv, H, N);
    agg1_kernel<<<(N + 3) / 4, 256, 0, stream>>>((const u32*)H, csr, row_start, dinv, b1f,
                                                 (u32*)H1, N);
    gemm_kernel<2, 4, 2><<<(N + 127) / 128, 256, 0, stream>>>(H1, flags + 1, B2p, dinv, H2, N);
    agg2_kernel<<<(N + 3) / 4, 256, 0, stream>>>((const u32*)H2, csr, row_start, dinv, b2f,
                                                 flags, (void*)d_out, N);
}